// Round 5
// baseline (292.660 us; speedup 1.0000x reference)
//
#include <hip/hip_runtime.h>
#include <hip/hip_bf16.h>
#include <math.h>

// MultiHeadSelfAttention: B=2,S=2048,D=1024,H=16,hd=64, fp32 in/out.
// bf16 MFMA everywhere; flash attention (S^T form) with no-max softmax.
// R16: macro-based ping-pong (R15's lambda-with-f32x16& refs caused scratch
// demotion: attn WRITE_SIZE 8192->35840 KB, FETCH 12.3->25.8 MB, dur 2x --
// traffic counters are clock-independent evidence; the 40ms gemm in the same
// profile was machine pathology). All register arrays now accessed via
// literal static names only (rule #20). Keeps R13's wins:
//  1) ping-pong sA/sB (static names via macro) kills the s_cur copy
//  2) s_setprio(1) around S-MFMA and PV-MFMA clusters (T5, attn +4-7%)
//  3) softmax pack via __float22bfloat162_rn (v_cvt_pk_bf16_f32: 1 op vs 3)
// R12 baseline counters: dur 51.7us, MfmaUtil 27.5%, VALU 52%, Occ 29%.
// SQ_LDS_BANK_CONFLICT = exactly 4 cyc per ds_read_b128 => intrinsic, not
// actionable.

typedef __bf16 bf16_t;
typedef __bf16 bf16x8 __attribute__((ext_vector_type(8)));
typedef float f32x4 __attribute__((ext_vector_type(4)));
typedef float f32x16 __attribute__((ext_vector_type(16)));
typedef unsigned u32x2 __attribute__((ext_vector_type(2)));

#define B_ 2
#define S_ 2048
#define D_ 1024
#define H_ 16
#define HD_ 64
// fold softmax scale (1/8) * log2(e) into Q so scores feed exp2 directly
#define QSCALE 0.18033688011112042f

__device__ __forceinline__ void load_lds16(const void* g, void* s) {
  // direct global->LDS DMA, 16B/lane; LDS dest is wave-uniform base + lane*16
  __builtin_amdgcn_global_load_lds((__attribute__((address_space(1))) unsigned int*)g,
                                   (__attribute__((address_space(3))) unsigned int*)s,
                                   16, 0, 0);
}

// fast fp32->bf16: round-to-nearest via +0x8000 (no NaN path; inputs finite).
__device__ __forceinline__ bf16_t fbf16(float x) {
  unsigned u = (__builtin_bit_cast(unsigned, x) + 0x8000u) >> 16;
  unsigned short s = (unsigned short)u;
  return __builtin_bit_cast(bf16_t, s);
}
// pack two fp32 -> bf16x2 in one v_perm_b32: result = {hi16(ub),hi16(ua)}
__device__ __forceinline__ unsigned pack_bf16x2(float a, float b) {
  unsigned ua = __builtin_bit_cast(unsigned, a) + 0x8000u;
  unsigned ub = __builtin_bit_cast(unsigned, b) + 0x8000u;
  return __builtin_amdgcn_perm(ub, ua, 0x07060302u);
}
// packed convert: compiler emits v_cvt_pk_bf16_f32 (RNE; 1 VALU op).
// __hip_bfloat162 is not trivially copyable -> memcpy, not bit_cast.
__device__ __forceinline__ unsigned cvt_pk_bf16x2(float a, float b) {
  __hip_bfloat162 h = __float22bfloat162_rn(make_float2(a, b));
  unsigned u;
  __builtin_memcpy(&u, &h, 4);
  return u;
}

// ---------------- fused fp32 -> bf16 convert (x, w_qkv, w_proj) ----------------
__global__ void tobf16_all(const float* __restrict__ x, const float* __restrict__ wq,
                           const float* __restrict__ wp, bf16_t* __restrict__ xb,
                           bf16_t* __restrict__ wqb, bf16_t* __restrict__ wpb) {
  int bid = blockIdx.x;
  const float* in;
  bf16_t* out;
  int base;
  if (bid < 4096) { in = x; out = xb; base = bid; }
  else if (bid < 7168) { in = wq; out = wqb; base = bid - 4096; }
  else { in = wp; out = wpb; base = bid - 7168; }
  int i = base * 256 + threadIdx.x;  // all three sizes are exact multiples of 256 float4
  float4 v = ((const float4*)in)[i];
  uint2 o;
  o.x = pack_bf16x2(v.x, v.y);
  o.y = pack_bf16x2(v.z, v.w);
  ((uint2*)out)[i] = o;
}

// ---------------- GEMM: C[M,N] = A[M,K] @ B[N,K]^T + bias ----------------
// 128xBN tile, BK=32, 256 threads (4 waves 2x2), double-buffered, one barrier
// per k-iter (drains DMA issued a full iter earlier). 16B-unit XOR swizzle.
// EPI=0: QKV epilogue (scatter to q/k/vT bf16 layouts, q pre-scaled), BN=128
// EPI=1: proj epilogue (fp32 out), BN=64 for 2x grid
template <int EPI, int BN>
__global__ __launch_bounds__(256, 2) void gemm_bt(
    const bf16_t* __restrict__ A, const bf16_t* __restrict__ Bm,
    const float* __restrict__ bias,
    bf16_t* __restrict__ qb, bf16_t* __restrict__ kb, bf16_t* __restrict__ vtb,
    float* __restrict__ outf) {
  constexpr int NI = BN / 32;            // n-fragments per wave
  constexpr int BUF = 8192 + BN * 64;    // bytes per buffer: A 8 KB + B BN*64
  __shared__ __align__(16) char smem[2 * BUF];
  const int tid = threadIdx.x;
  const int w = tid >> 6, lane = tid & 63;
  const int wm = w >> 1, wn = w & 1;
  const int quad = lane >> 4, l15 = lane & 15;
  const int m0 = blockIdx.y * 128, n0 = blockIdx.x * BN;

  auto stage = [&](int kt, int bb) {
    char* bA = smem + bb * BUF;
    char* bB = bA + 8192;
#pragma unroll
    for (int i = 0; i < 2; i++) {  // A: 512 units
      int ub = w * 128 + i * 64;
      int u = ub + lane;
      int r = u >> 2, c = (u & 3) ^ ((r >> 1) & 3);
      load_lds16(A + (size_t)(m0 + r) * 1024 + kt + c * 8, bA + (size_t)ub * 16);
    }
#pragma unroll
    for (int i = 0; i < BN / 64; i++) {  // B: BN*4 units
      int ub = w * (BN / 64) * 64 + i * 64;
      int u = ub + lane;
      int r = u >> 2, c = (u & 3) ^ ((r >> 1) & 3);
      load_lds16(Bm + (size_t)(n0 + r) * 1024 + kt + c * 8, bB + (size_t)ub * 16);
    }
  };

  f32x4 acc[4][NI];
#pragma unroll
  for (int mi = 0; mi < 4; mi++)
#pragma unroll
    for (int ni = 0; ni < NI; ni++) acc[mi][ni] = (f32x4){0.f, 0.f, 0.f, 0.f};

  stage(0, 0);  // prologue

  for (int it = 0; it < 32; it++) {
    __syncthreads();  // drains buf-it DMA (issued a full iter ago) + reuse sync
    if (it < 31) stage((it + 1) * 32, (it + 1) & 1);
    const bf16_t* bA = (const bf16_t*)(smem + (it & 1) * BUF);
    const bf16_t* bB = (const bf16_t*)(smem + (it & 1) * BUF + 8192);

    bf16x8 af[4], bfr[NI];
#pragma unroll
    for (int mi = 0; mi < 4; mi++) {
      int r = wm * 64 + mi * 16 + l15;
      af[mi] = *(const bf16x8*)(bA + (r * 4 + (quad ^ ((r >> 1) & 3))) * 8);
    }
#pragma unroll
    for (int ni = 0; ni < NI; ni++) {
      int r = wn * (BN / 2) + ni * 16 + l15;
      bfr[ni] = *(const bf16x8*)(bB + (r * 4 + (quad ^ ((r >> 1) & 3))) * 8);
    }
#pragma unroll
    for (int mi = 0; mi < 4; mi++)
#pragma unroll
      for (int ni = 0; ni < NI; ni++)
        acc[mi][ni] = __builtin_amdgcn_mfma_f32_16x16x32_bf16(af[mi], bfr[ni], acc[mi][ni], 0, 0, 0);
  }

  // epilogue: C row = m0+wm*64+mi*16+quad*4+r, col = n0+wn*(BN/2)+ni*16+l15
#pragma unroll
  for (int mi = 0; mi < 4; mi++) {
#pragma unroll
    for (int ni = 0; ni < NI; ni++) {
      int n = n0 + wn * (BN / 2) + ni * 16 + l15;
      float bv = bias[n];
#pragma unroll
      for (int r = 0; r < 4; r++) {
        int m = m0 + wm * 64 + mi * 16 + quad * 4 + r;
        float v = acc[mi][ni][r] + bv;
        if (EPI == 0) {
          int t = n >> 10;           // 0=Q,1=K,2=V (uniform per block: 128 | 1024)
          int rr = n & 1023;
          int hh = rr >> 6, d = rr & 63;
          int bb = m >> 11, s = m & 2047;
          size_t bh = (size_t)(bb * H_ + hh);
          if (t == 0)
            qb[(bh * S_ + s) * HD_ + d] = fbf16(v * QSCALE);
          else if (t == 1)
            kb[(bh * S_ + s) * HD_ + d] = fbf16(v);
          else
            vtb[(bh * HD_ + d) * S_ + s] = fbf16(v);  // V transposed for PV B-operand
        } else {
          outf[(size_t)m * 1024 + n] = v;
        }
      }
    }
  }
}

// ---------------- flash attention (S^T form, kv-split, 2-stage pipelined) -------
// 1D grid of 1024; gid%8 = XCD: XCD g owns bh in [4g,4g+4) -> 2 MB K/V per XCD.
// block = (b,h, q-tile 64), 256 threads = 4 waves:
//   wave w: q-band (w&1)*32, kv-half (w>>1)*1024.  Each pair (waves 2p,2p+1)
//   runs its own dbuf pipeline over 32 kv-tiles of 32 (16 KB LDS per pair).
// S^T = K Q^T: A = K rows (m=kv 0..31, LDS), B = Q rows (n=q, regs).
// C/D 32x32: col=lane&31=q, row=kv=(reg&3)+8*(reg>>2)+4*h2  [m74/m101 layout].
// PIPELINE: iter j holds S(j) in SCUR; av(j) read PRE-barrier (protects regs
// from stage(j+2) -> buf j&1), then barrier, stage(j+2), ak(j+1) reads +
// S(j+1) MFMAs | softmax(j) | PV(j).  Ping-pong via ATTN_BODY macro with
// literal register names (NO reference params -- R15's lambda refs demoted
// sA/sB to scratch: +27MB WRITE_SIZE).  MFMA clusters in s_setprio(1).
// Max-free softmax => pair partials (O^T, l) combine by addition via LDS.

// One pipeline step. J: runtime iter index; SCUR/SNEXT: literal f32x16 names.
#define ATTN_BODY(J, SCUR, SNEXT)                                              \
  do {                                                                         \
    const int j_ = (J);                                                        \
    const bf16_t* bV = (const bf16_t*)(pbase + (j_ & 1) * 8192 + 4096);        \
    bf16x8 av00, av01, av10, av11; /* [dt][ks], static names */                \
    {                                                                          \
      int r0 = l31, r1 = 32 + l31;                                             \
      int c0 = h2, c1 = 2 + h2;                                                \
      av00 = *(const bf16x8*)(bV + (r0 * 4 + (c0 ^ ((r0 >> 1) & 3))) * 8);     \
      av10 = *(const bf16x8*)(bV + (r1 * 4 + (c0 ^ ((r1 >> 1) & 3))) * 8);     \
      av01 = *(const bf16x8*)(bV + (r0 * 4 + (c1 ^ ((r0 >> 1) & 3))) * 8);     \
      av11 = *(const bf16x8*)(bV + (r1 * 4 + (c1 ^ ((r1 >> 1) & 3))) * 8);     \
    }                                                                          \
    __syncthreads(); /* drains stage(j+1) DMA; av(j)/ak(j) reads done */       \
    if (j_ < 30) stage(kvbase + (j_ + 2) * 32, j_ & 1);                        \
    if (j_ < 31) {                                                             \
      const bf16_t* bK1 = (const bf16_t*)(pbase + ((j_ + 1) & 1) * 8192);      \
      _Pragma("unroll")                                                        \
      for (int i = 0; i < 16; i++) SNEXT[i] = 0.f;                             \
      __builtin_amdgcn_s_setprio(1);                                           \
      _Pragma("unroll")                                                        \
      for (int ks = 0; ks < 4; ks++) {                                         \
        int r = l31, c = ks * 2 + h2;                                          \
        bf16x8 ak = *(const bf16x8*)(bK1 + (r * 8 + (c ^ (r & 7))) * 8);       \
        SNEXT = __builtin_amdgcn_mfma_f32_32x32x16_bf16(ak, bq[ks], SNEXT, 0, 0, 0); \
      }                                                                        \
      __builtin_amdgcn_s_setprio(0);                                           \
    }                                                                          \
    unsigned pk[8];                                                            \
    float ls = 0.f;                                                            \
    _Pragma("unroll")                                                          \
    for (int i = 0; i < 8; i++) {                                              \
      float p0 = __builtin_amdgcn_exp2f(SCUR[2 * i]);                          \
      float p1 = __builtin_amdgcn_exp2f(SCUR[2 * i + 1]);                      \
      ls += p0 + p1;                                                           \
      pk[i] = cvt_pk_bf16x2(p0, p1);                                           \
    }                                                                          \
    l_acc += ls;                                                               \
    bf16x8 bp[2];                                                              \
    _Pragma("unroll")                                                          \
    for (int kk = 0; kk < 2; kk++) {                                           \
      unsigned a0 = pk[kk * 4 + 0], a1 = pk[kk * 4 + 1];                       \
      unsigned a2 = pk[kk * 4 + 2], a3 = pk[kk * 4 + 3];                       \
      u32x2 r02 = __builtin_amdgcn_permlane32_swap(a0, a2, false, false);      \
      u32x2 r13 = __builtin_amdgcn_permlane32_swap(a1, a3, false, false);      \
      union { unsigned u[4]; bf16x8 v; } ub_;                                  \
      ub_.u[0] = r02[0];                                                       \
      ub_.u[1] = r13[0];                                                       \
      ub_.u[2] = r02[1];                                                       \
      ub_.u[3] = r13[1];                                                       \
      bp[kk] = ub_.v;                                                          \
    }                                                                          \
    __builtin_amdgcn_s_setprio(1);                                             \
    acc_o[0] = __builtin_amdgcn_mfma_f32_32x32x16_bf16(av00, bp[0], acc_o[0], 0, 0, 0); \
    acc_o[1] = __builtin_amdgcn_mfma_f32_32x32x16_bf16(av10, bp[0], acc_o[1], 0, 0, 0); \
    acc_o[0] = __builtin_amdgcn_mfma_f32_32x32x16_bf16(av01, bp[1], acc_o[0], 0, 0, 0); \
    acc_o[1] = __builtin_amdgcn_mfma_f32_32x32x16_bf16(av11, bp[1], acc_o[1], 0, 0, 0); \
    __builtin_amdgcn_s_setprio(0);                                             \
  } while (0)

__global__ __launch_bounds__(256, 4) void attn(
    const bf16_t* __restrict__ qb, const bf16_t* __restrict__ kb,
    const bf16_t* __restrict__ vtb, bf16_t* __restrict__ ob) {
  __shared__ __align__(16) char smem[32768];
  const int tid = threadIdx.x, w = tid >> 6, lane = tid & 63;
  const int h2 = lane >> 5, l31 = lane & 31;
  const int qband = w & 1, pair = w >> 1;
  // XCD-aware decode: gid%8 = XCD; 4 bh x 32 q-tiles per XCD.
  const int gid = blockIdx.x;
  const int g = gid & 7, k_ = gid >> 3;
  const int bh = g * 4 + (k_ >> 5);
  const int qt = k_ & 31;
  const int b = bh >> 4, h = bh & 15;
  const size_t base = (size_t)bh * S_ * HD_;
  const size_t vbase = (size_t)bh * HD_ * S_;
  const int q0 = qt * 64;
  const int myq = q0 + qband * 32 + l31;  // this lane's q column
  const int kvbase = pair << 10;          // this wave's kv-half
  char* pbase = smem + pair * 16384;      // per-pair LDS: 2 bufs x (K 4K | V 4K)

  // Q B-frags (loop-invariant): B[n=q=l31][k=ks*16+h2*8+j]
  bf16x8 bq[4];
#pragma unroll
  for (int ks = 0; ks < 4; ks++)
    bq[ks] = *(const bf16x8*)(qb + base + (size_t)myq * 64 + ks * 16 + h2 * 8);

  // stage K[32 kv x 64 d] + V^T[64 d x 32 kv] into pair buffer bb.
  // K rows: 8 units/row, sigma(r)=r&7. V rows: 4 units/row, sigma(r)=(r>>1)&3.
  auto stage = [&](int kv0, int bb) {
    char* bK = pbase + bb * 8192;
    char* bV = bK + 4096;
#pragma unroll
    for (int i = 0; i < 2; i++) {
      int ub = qband * 64 + i * 128;
      int u = ub + lane;
      {
        int r = u >> 3, c = (u & 7) ^ (r & 7);
        load_lds16(kb + base + (size_t)(kv0 + r) * 64 + c * 8, bK + (size_t)ub * 16);
      }
      {
        int r = u >> 2, c = (u & 3) ^ ((r >> 1) & 3);
        load_lds16(vtb + vbase + (size_t)r * S_ + kv0 + c * 8, bV + (size_t)ub * 16);
      }
    }
  };

  f32x16 acc_o[2];
#pragma unroll
  for (int dt = 0; dt < 2; dt++)
#pragma unroll
    for (int i = 0; i < 16; i++) acc_o[dt][i] = 0.f;
  float l_acc = 0.f;  // per-lane: sum of p over this lane's kv rows, for q=myq

  // prologue: tile 0 staged+drained; tile 1 DMA in flight; sA = S(0)
  stage(kvbase, 0);
  __syncthreads();
  stage(kvbase + 32, 1);
  f32x16 sA, sB;
  {
    const bf16_t* bK = (const bf16_t*)pbase;
#pragma unroll
    for (int i = 0; i < 16; i++) sA[i] = 0.f;
#pragma unroll
    for (int ks = 0; ks < 4; ks++) {
      int r = l31, c = ks * 2 + h2;
      bf16x8 ak = *(const bf16x8*)(bK + (r * 8 + (c ^ (r & 7))) * 8);
      sA = __builtin_amdgcn_mfma_f32_32x32x16_bf16(ak, bq[ks], sA, 0, 0, 0);
    }
  }

  // ping-pong: even j consumes sA, fills sB; odd j swaps. Literal names only.
  for (int j = 0; j < 32; j += 2) {
    ATTN_BODY(j, sA, sB);
    ATTN_BODY(j + 1, sB, sA);
  }

  // within-pair denominator: lane + h2-partner cover all kv rows of this half
  float l_pair = l_acc + (float)__shfl_xor(l_acc, 32);

  // cross-pair combine via LDS (K/V buffers dead after last in-loop barrier).
  // stride 33 floats -> conflict-free. Region: 2 qbands x 64 lanes x 33 f32.
  float* red = (float*)smem;
  const int rbase = qband * (64 * 33) + lane * 33;
  if (pair == 1) {
#pragma unroll
    for (int dt = 0; dt < 2; dt++)
#pragma unroll
      for (int i = 0; i < 16; i++) red[rbase + dt * 16 + i] = acc_o[dt][i];
    red[rbase + 32] = l_pair;
  }
  __syncthreads();
  if (pair == 0) {
#pragma unroll
    for (int dt = 0; dt < 2; dt++)
#pragma unroll
      for (int i = 0; i < 16; i++) acc_o[dt][i] += red[rbase + dt * 16 + i];
    float inv = 1.0f / (l_pair + red[rbase + 32]);

    // epilogue: O^T col q = myq (lane), rows d = dt*32 + 8*g4 + 4*h2 + (0..3)
#pragma unroll
    for (int dt = 0; dt < 2; dt++)
#pragma unroll
      for (int g4 = 0; g4 < 4; g4++) {
        uint2 o;
        o.x = pack_bf16x2(acc_o[dt][g4 * 4 + 0] * inv, acc_o[dt][g4 * 4 + 1] * inv);
        o.y = pack_bf16x2(acc_o[dt][g4 * 4 + 2] * inv, acc_o[dt][g4 * 4 + 3] * inv);
        int d = dt * 32 + g4 * 8 + h2 * 4;
        *(uint2*)(ob + ((size_t)b * S_ + myq) * D_ + h * HD_ + d) = o;
      }
  }
}

// ---------------- launcher ----------------
extern "C" void kernel_launch(void* const* d_in, const int* in_sizes, int n_in,
                              void* d_out, int out_size, void* d_ws, size_t ws_size,
                              hipStream_t stream) {
  const float* x = (const float*)d_in[0];        // [2,2048,1024]
  const float* w_qkv = (const float*)d_in[1];    // [3072,1024]
  const float* b_qkv = (const float*)d_in[2];    // [3072]
  const float* w_proj = (const float*)d_in[3];   // [1024,1024]
  const float* b_proj = (const float*)d_in[4];   // [1024]
  float* out = (float*)d_out;

  char* ws = (char*)d_ws;
  size_t off = 0;
  bf16_t* xb = (bf16_t*)(ws + off); off += (size_t)4096 * 1024 * 2;    // 8 MB
  bf16_t* wqkvb = (bf16_t*)(ws + off); off += (size_t)3072 * 1024 * 2; // 6 MB
  bf16_t* wpb = (bf16_t*)(ws + off); off += (size_t)1024 * 1024 * 2;   // 2 MB
  bf16_t* qb = (bf16_t*)(ws + off); off += (size_t)4096 * 1024 * 2;    // 8 MB [B,H,S,hd]
  bf16_t* kb = (bf16_t*)(ws + off); off += (size_t)4096 * 1024 * 2;    // 8 MB [B,H,S,hd]
  bf16_t* vtb = (bf16_t*)(ws + off); off += (size_t)4096 * 1024 * 2;   // 8 MB [B,H,hd,S]
  bf16_t* ob = xb;  // xb dead after QKV GEMM; reuse for attention output
  // total ws use: 41,943,040 B

  tobf16_all<<<8192, 256, 0, stream>>>(x, w_qkv, w_proj, xb, wqkvb, wpb);
  gemm_bt<0, 128><<<dim3(24, 32), 256, 0, stream>>>(xb, wqkvb, b_qkv, qb, kb, vtb, nullptr);
  attn<<<1024, 256, 0, stream>>>(qb, kb, vtb, ob);
  gemm_bt<1, 64><<<dim3(16, 32), 256, 0, stream>>>(ob, wpb, b_proj, nullptr, nullptr, nullptr, out);
}

// Round 6
// 191.422 us; speedup vs baseline: 1.5289x; 1.5289x over previous
//
#include <hip/hip_runtime.h>
#include <hip/hip_bf16.h>
#include <math.h>

// MultiHeadSelfAttention: B=2,S=2048,D=1024,H=16,hd=64, fp32 in/out.
// bf16 MFMA everywhere; flash attention (S^T form) with no-max softmax.
// R17 = R12 attn structure (proven: 51.7us, clean traffic) + setprio ONLY.
// History: R15 (lambda-ref ping-pong + setprio + cvt_pk) -> +27MB scratch
// writes; R16 (macro ping-pong + setprio + cvt_pk) -> +195MB scratch, 160us.
// Ping-pong (2x-inlined body w/ cross-body conditional live ranges) and
// cvt_pk-via-memcpy (non-trivially-copyable __hip_bfloat162, address taken)
// are the scratch suspects -- both permanently reverted. The s_cur=s_next
// copy costs only ~1.7us; not worth touching. This round isolates setprio:
// if WRITE_SIZE != 8192 KB, setprio is the trigger and gets dropped too.

typedef __bf16 bf16_t;
typedef __bf16 bf16x8 __attribute__((ext_vector_type(8)));
typedef float f32x4 __attribute__((ext_vector_type(4)));
typedef float f32x16 __attribute__((ext_vector_type(16)));
typedef unsigned u32x2 __attribute__((ext_vector_type(2)));

#define B_ 2
#define S_ 2048
#define D_ 1024
#define H_ 16
#define HD_ 64
// fold softmax scale (1/8) * log2(e) into Q so scores feed exp2 directly
#define QSCALE 0.18033688011112042f

__device__ __forceinline__ void load_lds16(const void* g, void* s) {
  // direct global->LDS DMA, 16B/lane; LDS dest is wave-uniform base + lane*16
  __builtin_amdgcn_global_load_lds((__attribute__((address_space(1))) unsigned int*)g,
                                   (__attribute__((address_space(3))) unsigned int*)s,
                                   16, 0, 0);
}

// fast fp32->bf16: round-to-nearest via +0x8000 (no NaN path; inputs finite).
__device__ __forceinline__ bf16_t fbf16(float x) {
  unsigned u = (__builtin_bit_cast(unsigned, x) + 0x8000u) >> 16;
  unsigned short s = (unsigned short)u;
  return __builtin_bit_cast(bf16_t, s);
}
// pack two fp32 -> bf16x2 in one v_perm_b32: result = {hi16(ub),hi16(ua)}
__device__ __forceinline__ unsigned pack_bf16x2(float a, float b) {
  unsigned ua = __builtin_bit_cast(unsigned, a) + 0x8000u;
  unsigned ub = __builtin_bit_cast(unsigned, b) + 0x8000u;
  return __builtin_amdgcn_perm(ub, ua, 0x07060302u);
}

// ---------------- fused fp32 -> bf16 convert (x, w_qkv, w_proj) ----------------
__global__ void tobf16_all(const float* __restrict__ x, const float* __restrict__ wq,
                           const float* __restrict__ wp, bf16_t* __restrict__ xb,
                           bf16_t* __restrict__ wqb, bf16_t* __restrict__ wpb) {
  int bid = blockIdx.x;
  const float* in;
  bf16_t* out;
  int base;
  if (bid < 4096) { in = x; out = xb; base = bid; }
  else if (bid < 7168) { in = wq; out = wqb; base = bid - 4096; }
  else { in = wp; out = wpb; base = bid - 7168; }
  int i = base * 256 + threadIdx.x;  // all three sizes are exact multiples of 256 float4
  float4 v = ((const float4*)in)[i];
  uint2 o;
  o.x = pack_bf16x2(v.x, v.y);
  o.y = pack_bf16x2(v.z, v.w);
  ((uint2*)out)[i] = o;
}

// ---------------- GEMM: C[M,N] = A[M,K] @ B[N,K]^T + bias ----------------
// 128xBN tile, BK=32, 256 threads (4 waves 2x2), double-buffered, one barrier
// per k-iter (drains DMA issued a full iter earlier). 16B-unit XOR swizzle.
// EPI=0: QKV epilogue (scatter to q/k/vT bf16 layouts, q pre-scaled), BN=128
// EPI=1: proj epilogue (fp32 out), BN=64 for 2x grid
template <int EPI, int BN>
__global__ __launch_bounds__(256, 2) void gemm_bt(
    const bf16_t* __restrict__ A, const bf16_t* __restrict__ Bm,
    const float* __restrict__ bias,
    bf16_t* __restrict__ qb, bf16_t* __restrict__ kb, bf16_t* __restrict__ vtb,
    float* __restrict__ outf) {
  constexpr int NI = BN / 32;            // n-fragments per wave
  constexpr int BUF = 8192 + BN * 64;    // bytes per buffer: A 8 KB + B BN*64
  __shared__ __align__(16) char smem[2 * BUF];
  const int tid = threadIdx.x;
  const int w = tid >> 6, lane = tid & 63;
  const int wm = w >> 1, wn = w & 1;
  const int quad = lane >> 4, l15 = lane & 15;
  const int m0 = blockIdx.y * 128, n0 = blockIdx.x * BN;

  auto stage = [&](int kt, int bb) {
    char* bA = smem + bb * BUF;
    char* bB = bA + 8192;
#pragma unroll
    for (int i = 0; i < 2; i++) {  // A: 512 units
      int ub = w * 128 + i * 64;
      int u = ub + lane;
      int r = u >> 2, c = (u & 3) ^ ((r >> 1) & 3);
      load_lds16(A + (size_t)(m0 + r) * 1024 + kt + c * 8, bA + (size_t)ub * 16);
    }
#pragma unroll
    for (int i = 0; i < BN / 64; i++) {  // B: BN*4 units
      int ub = w * (BN / 64) * 64 + i * 64;
      int u = ub + lane;
      int r = u >> 2, c = (u & 3) ^ ((r >> 1) & 3);
      load_lds16(Bm + (size_t)(n0 + r) * 1024 + kt + c * 8, bB + (size_t)ub * 16);
    }
  };

  f32x4 acc[4][NI];
#pragma unroll
  for (int mi = 0; mi < 4; mi++)
#pragma unroll
    for (int ni = 0; ni < NI; ni++) acc[mi][ni] = (f32x4){0.f, 0.f, 0.f, 0.f};

  stage(0, 0);  // prologue

  for (int it = 0; it < 32; it++) {
    __syncthreads();  // drains buf-it DMA (issued a full iter ago) + reuse sync
    if (it < 31) stage((it + 1) * 32, (it + 1) & 1);
    const bf16_t* bA = (const bf16_t*)(smem + (it & 1) * BUF);
    const bf16_t* bB = (const bf16_t*)(smem + (it & 1) * BUF + 8192);

    bf16x8 af[4], bfr[NI];
#pragma unroll
    for (int mi = 0; mi < 4; mi++) {
      int r = wm * 64 + mi * 16 + l15;
      af[mi] = *(const bf16x8*)(bA + (r * 4 + (quad ^ ((r >> 1) & 3))) * 8);
    }
#pragma unroll
    for (int ni = 0; ni < NI; ni++) {
      int r = wn * (BN / 2) + ni * 16 + l15;
      bfr[ni] = *(const bf16x8*)(bB + (r * 4 + (quad ^ ((r >> 1) & 3))) * 8);
    }
#pragma unroll
    for (int mi = 0; mi < 4; mi++)
#pragma unroll
      for (int ni = 0; ni < NI; ni++)
        acc[mi][ni] = __builtin_amdgcn_mfma_f32_16x16x32_bf16(af[mi], bfr[ni], acc[mi][ni], 0, 0, 0);
  }

  // epilogue: C row = m0+wm*64+mi*16+quad*4+r, col = n0+wn*(BN/2)+ni*16+l15
#pragma unroll
  for (int mi = 0; mi < 4; mi++) {
#pragma unroll
    for (int ni = 0; ni < NI; ni++) {
      int n = n0 + wn * (BN / 2) + ni * 16 + l15;
      float bv = bias[n];
#pragma unroll
      for (int r = 0; r < 4; r++) {
        int m = m0 + wm * 64 + mi * 16 + quad * 4 + r;
        float v = acc[mi][ni][r] + bv;
        if (EPI == 0) {
          int t = n >> 10;           // 0=Q,1=K,2=V (uniform per block: 128 | 1024)
          int rr = n & 1023;
          int hh = rr >> 6, d = rr & 63;
          int bb = m >> 11, s = m & 2047;
          size_t bh = (size_t)(bb * H_ + hh);
          if (t == 0)
            qb[(bh * S_ + s) * HD_ + d] = fbf16(v * QSCALE);
          else if (t == 1)
            kb[(bh * S_ + s) * HD_ + d] = fbf16(v);
          else
            vtb[(bh * HD_ + d) * S_ + s] = fbf16(v);  // V transposed for PV B-operand
        } else {
          outf[(size_t)m * 1024 + n] = v;
        }
      }
    }
  }
}

// ---------------- flash attention (S^T form, kv-split, 2-stage pipelined) -------
// 1D grid of 1024; gid%8 = XCD: XCD g owns bh in [4g,4g+4) -> 2 MB K/V per XCD.
// block = (b,h, q-tile 64), 256 threads = 4 waves:
//   wave w: q-band (w&1)*32, kv-half (w>>1)*1024.  Each pair (waves 2p,2p+1)
//   runs its own dbuf pipeline over 32 kv-tiles of 32 (16 KB LDS per pair).
// S^T = K Q^T: A = K rows (m=kv 0..31, LDS), B = Q rows (n=q, regs).
// C/D 32x32: col=lane&31=q, row=kv=(reg&3)+8*(reg>>2)+4*h2  [m74/m101 layout].
// PIPELINE: iter j holds S_cur=S(j); av(j) read PRE-barrier (protects regs
// from stage(j+2) -> buf j&1), then barrier, stage(j+2), ak(j+1) reads +
// S(j+1) MFMAs | softmax(j) | PV(j). Single body, s_cur=s_next copy (R12
// form -- both ping-pong variants caused scratch explosions, see header).
// ONLY new thing vs R12: s_setprio(1) around the two MFMA clusters.
__global__ __launch_bounds__(256, 4) void attn(
    const bf16_t* __restrict__ qb, const bf16_t* __restrict__ kb,
    const bf16_t* __restrict__ vtb, bf16_t* __restrict__ ob) {
  __shared__ __align__(16) char smem[32768];
  const int tid = threadIdx.x, w = tid >> 6, lane = tid & 63;
  const int h2 = lane >> 5, l31 = lane & 31;
  const int qband = w & 1, pair = w >> 1;
  // XCD-aware decode: gid%8 = XCD; 4 bh x 32 q-tiles per XCD.
  const int gid = blockIdx.x;
  const int g = gid & 7, k_ = gid >> 3;
  const int bh = g * 4 + (k_ >> 5);
  const int qt = k_ & 31;
  const int b = bh >> 4, h = bh & 15;
  const size_t base = (size_t)bh * S_ * HD_;
  const size_t vbase = (size_t)bh * HD_ * S_;
  const int q0 = qt * 64;
  const int myq = q0 + qband * 32 + l31;  // this lane's q column
  const int kvbase = pair << 10;          // this wave's kv-half
  char* pbase = smem + pair * 16384;      // per-pair LDS: 2 bufs x (K 4K | V 4K)

  // Q B-frags (loop-invariant): B[n=q=l31][k=ks*16+h2*8+j]
  bf16x8 bq[4];
#pragma unroll
  for (int ks = 0; ks < 4; ks++)
    bq[ks] = *(const bf16x8*)(qb + base + (size_t)myq * 64 + ks * 16 + h2 * 8);

  // stage K[32 kv x 64 d] + V^T[64 d x 32 kv] into pair buffer bb.
  // K rows: 8 units/row, sigma(r)=r&7. V rows: 4 units/row, sigma(r)=(r>>1)&3.
  auto stage = [&](int kv0, int bb) {
    char* bK = pbase + bb * 8192;
    char* bV = bK + 4096;
#pragma unroll
    for (int i = 0; i < 2; i++) {
      int ub = qband * 64 + i * 128;
      int u = ub + lane;
      {
        int r = u >> 3, c = (u & 7) ^ (r & 7);
        load_lds16(kb + base + (size_t)(kv0 + r) * 64 + c * 8, bK + (size_t)ub * 16);
      }
      {
        int r = u >> 2, c = (u & 3) ^ ((r >> 1) & 3);
        load_lds16(vtb + vbase + (size_t)r * S_ + kv0 + c * 8, bV + (size_t)ub * 16);
      }
    }
  };

  f32x16 acc_o[2];
#pragma unroll
  for (int dt = 0; dt < 2; dt++)
#pragma unroll
    for (int i = 0; i < 16; i++) acc_o[dt][i] = 0.f;
  float l_acc = 0.f;  // per-lane: sum of p over this lane's kv rows, for q=myq

  // prologue: tile 0 staged+drained; tile 1 DMA in flight; s_cur = S(0)
  stage(kvbase, 0);
  __syncthreads();
  stage(kvbase + 32, 1);
  f32x16 s_cur;
  {
    const bf16_t* bK = (const bf16_t*)pbase;
#pragma unroll
    for (int i = 0; i < 16; i++) s_cur[i] = 0.f;
#pragma unroll
    for (int ks = 0; ks < 4; ks++) {
      int r = l31, c = ks * 2 + h2;
      bf16x8 ak = *(const bf16x8*)(bK + (r * 8 + (c ^ (r & 7))) * 8);
      s_cur = __builtin_amdgcn_mfma_f32_32x32x16_bf16(ak, bq[ks], s_cur, 0, 0, 0);
    }
  }

  for (int j = 0; j < 32; j++) {
    // V^T(j) A-frags PRE-barrier: tile j was drained at the previous barrier;
    // regs protect against stage(j+2) overwriting buf j&1 mid-iter.
    const bf16_t* bV = (const bf16_t*)(pbase + (j & 1) * 8192 + 4096);
    bf16x8 av[2][2];
#pragma unroll
    for (int ks = 0; ks < 2; ks++)
#pragma unroll
      for (int dt = 0; dt < 2; dt++) {
        int r = dt * 32 + l31, c = ks * 2 + h2;
        av[dt][ks] = *(const bf16x8*)(bV + (r * 4 + (c ^ ((r >> 1) & 3))) * 8);
      }

    __syncthreads();  // drains stage(j+1) DMA; all waves' av(j)/ak(j) reads done
    if (j < 30) stage(kvbase + (j + 2) * 32, j & 1);

    // S(j+1) = K(j+1) Q^T — independent of softmax(j) and PV(j)
    f32x16 s_next;
    if (j < 31) {
      const bf16_t* bK1 = (const bf16_t*)(pbase + ((j + 1) & 1) * 8192);
#pragma unroll
      for (int i = 0; i < 16; i++) s_next[i] = 0.f;
      __builtin_amdgcn_s_setprio(1);
#pragma unroll
      for (int ks = 0; ks < 4; ks++) {
        int r = l31, c = ks * 2 + h2;
        bf16x8 ak = *(const bf16x8*)(bK1 + (r * 8 + (c ^ (r & 7))) * 8);
        s_next = __builtin_amdgcn_mfma_f32_32x32x16_bf16(ak, bq[ks], s_next, 0, 0, 0);
      }
      __builtin_amdgcn_s_setprio(0);
    }

    // no-max softmax on s_cur (native exp2) + pack reg-pairs (adjacent kv)
    unsigned pk[8];
    float ls = 0.f;
#pragma unroll
    for (int i = 0; i < 8; i++) {
      float p0 = __builtin_amdgcn_exp2f(s_cur[2 * i]);
      float p1 = __builtin_amdgcn_exp2f(s_cur[2 * i + 1]);
      ls += p0 + p1;
      pk[i] = pack_bf16x2(p0, p1);
    }
    l_acc += ls;

    // build P^T B-frags: per 16-kv step, exchange packs across lane-halves.
    // permlane32_swap(a,b): dst0 = {a_lo | b_lo->hi}, dst1 = {a_hi->lo | b_hi}
    bf16x8 bp[2];
#pragma unroll
    for (int kk = 0; kk < 2; kk++) {
      unsigned a0 = pk[kk * 4 + 0], a1 = pk[kk * 4 + 1];
      unsigned a2 = pk[kk * 4 + 2], a3 = pk[kk * 4 + 3];
      u32x2 r02 = __builtin_amdgcn_permlane32_swap(a0, a2, false, false);
      u32x2 r13 = __builtin_amdgcn_permlane32_swap(a1, a3, false, false);
      union { unsigned u[4]; bf16x8 v; } bb;
      bb.u[0] = r02[0];
      bb.u[1] = r13[0];
      bb.u[2] = r02[1];
      bb.u[3] = r13[1];
      bp[kk] = bb.v;
    }

    // O^T += V^T(j) P^T(j)
    __builtin_amdgcn_s_setprio(1);
#pragma unroll
    for (int ks = 0; ks < 2; ks++)
#pragma unroll
      for (int dt = 0; dt < 2; dt++)
        acc_o[dt] = __builtin_amdgcn_mfma_f32_32x32x16_bf16(av[dt][ks], bp[ks], acc_o[dt], 0, 0, 0);
    __builtin_amdgcn_s_setprio(0);

    if (j < 31) s_cur = s_next;
  }

  // within-pair denominator: lane + h2-partner cover all kv rows of this half
  float l_pair = l_acc + (float)__shfl_xor(l_acc, 32);

  // cross-pair combine via LDS (K/V buffers dead after last in-loop barrier).
  // stride 33 floats -> conflict-free. Region: 2 qbands x 64 lanes x 33 f32.
  float* red = (float*)smem;
  const int rbase = qband * (64 * 33) + lane * 33;
  if (pair == 1) {
#pragma unroll
    for (int dt = 0; dt < 2; dt++)
#pragma unroll
      for (int i = 0; i < 16; i++) red[rbase + dt * 16 + i] = acc_o[dt][i];
    red[rbase + 32] = l_pair;
  }
  __syncthreads();
  if (pair == 0) {
#pragma unroll
    for (int dt = 0; dt < 2; dt++)
#pragma unroll
      for (int i = 0; i < 16; i++) acc_o[dt][i] += red[rbase + dt * 16 + i];
    float inv = 1.0f / (l_pair + red[rbase + 32]);

    // epilogue: O^T col q = myq (lane), rows d = dt*32 + 8*g4 + 4*h2 + (0..3)
#pragma unroll
    for (int dt = 0; dt < 2; dt++)
#pragma unroll
      for (int g4 = 0; g4 < 4; g4++) {
        uint2 o;
        o.x = pack_bf16x2(acc_o[dt][g4 * 4 + 0] * inv, acc_o[dt][g4 * 4 + 1] * inv);
        o.y = pack_bf16x2(acc_o[dt][g4 * 4 + 2] * inv, acc_o[dt][g4 * 4 + 3] * inv);
        int d = dt * 32 + g4 * 8 + h2 * 4;
        *(uint2*)(ob + ((size_t)b * S_ + myq) * D_ + h * HD_ + d) = o;
      }
  }
}

// ---------------- launcher ----------------
extern "C" void kernel_launch(void* const* d_in, const int* in_sizes, int n_in,
                              void* d_out, int out_size, void* d_ws, size_t ws_size,
                              hipStream_t stream) {
  const float* x = (const float*)d_in[0];        // [2,2048,1024]
  const float* w_qkv = (const float*)d_in[1];    // [3072,1024]
  const float* b_qkv = (const float*)d_in[2];    // [3072]
  const float* w_proj = (const float*)d_in[3];   // [1024,1024]
  const float* b_proj = (const float*)d_in[4];   // [1024]
  float* out = (float*)d_out;

  char* ws = (char*)d_ws;
  size_t off = 0;
  bf16_t* xb = (bf16_t*)(ws + off); off += (size_t)4096 * 1024 * 2;    // 8 MB
  bf16_t* wqkvb = (bf16_t*)(ws + off); off += (size_t)3072 * 1024 * 2; // 6 MB
  bf16_t* wpb = (bf16_t*)(ws + off); off += (size_t)1024 * 1024 * 2;   // 2 MB
  bf16_t* qb = (bf16_t*)(ws + off); off += (size_t)4096 * 1024 * 2;    // 8 MB [B,H,S,hd]
  bf16_t* kb = (bf16_t*)(ws + off); off += (size_t)4096 * 1024 * 2;    // 8 MB [B,H,S,hd]
  bf16_t* vtb = (bf16_t*)(ws + off); off += (size_t)4096 * 1024 * 2;   // 8 MB [B,H,hd,S]
  bf16_t* ob = xb;  // xb dead after QKV GEMM; reuse for attention output
  // total ws use: 41,943,040 B

  tobf16_all<<<8192, 256, 0, stream>>>(x, w_qkv, w_proj, xb, wqkvb, wpb);
  gemm_bt<0, 128><<<dim3(24, 32), 256, 0, stream>>>(xb, wqkvb, b_qkv, qb, kb, vtb, nullptr);
  attn<<<1024, 256, 0, stream>>>(qb, kb, vtb, ob);
  gemm_bt<1, 64><<<dim3(16, 32), 256, 0, stream>>>(ob, wpb, b_proj, nullptr, nullptr, nullptr, out);
}

// Round 7
// 189.512 us; speedup vs baseline: 1.5443x; 1.0101x over previous
//
#include <hip/hip_runtime.h>
#include <hip/hip_bf16.h>
#include <math.h>

// MultiHeadSelfAttention: B=2,S=2048,D=1024,H=16,hd=64, fp32 in/out.
// bf16 MFMA everywhere; flash attention (S^T form) with no-max softmax.
// R18 = exact R12 revert (best measured: attn 51.7us, total 188.2us).
// Micro-opt ledger on this structure (all within-harness measured):
//   R12 kv-split 4-wave occupancy 2x:          63 -> 51.7us   WIN
//   R13/R15 lambda-ref ping-pong:              scratch +27MB  FAIL
//   R16 macro ping-pong (cond. live ranges):   scratch +195MB FAIL
//   R17 s_setprio around MFMA clusters:        51.7 -> 58.9us FAIL
//     (barrier-locked waves each iter => no role diversity; setprio only
//      delays partner waves' global_load_lds issue. T5 prereq not met.)
// SQ_LDS_BANK_CONFLICT = exactly 4 cyc per ds_read_b128 (R11+R12 both)
// => intrinsic wave64 b128 cost, NOT a fixable conflict.
// R12 floors: MFMA 13.8us, trans(exp2) ~7us, LDS pipe ~20us, VALU ~27us
// busy -- overlapped into 51.7us at 16 waves/CU (grid-capped).

typedef __bf16 bf16_t;
typedef __bf16 bf16x8 __attribute__((ext_vector_type(8)));
typedef float f32x4 __attribute__((ext_vector_type(4)));
typedef float f32x16 __attribute__((ext_vector_type(16)));
typedef unsigned u32x2 __attribute__((ext_vector_type(2)));

#define B_ 2
#define S_ 2048
#define D_ 1024
#define H_ 16
#define HD_ 64
// fold softmax scale (1/8) * log2(e) into Q so scores feed exp2 directly
#define QSCALE 0.18033688011112042f

__device__ __forceinline__ void load_lds16(const void* g, void* s) {
  // direct global->LDS DMA, 16B/lane; LDS dest is wave-uniform base + lane*16
  __builtin_amdgcn_global_load_lds((__attribute__((address_space(1))) unsigned int*)g,
                                   (__attribute__((address_space(3))) unsigned int*)s,
                                   16, 0, 0);
}

// fast fp32->bf16: round-to-nearest via +0x8000 (no NaN path; inputs finite).
__device__ __forceinline__ bf16_t fbf16(float x) {
  unsigned u = (__builtin_bit_cast(unsigned, x) + 0x8000u) >> 16;
  unsigned short s = (unsigned short)u;
  return __builtin_bit_cast(bf16_t, s);
}
// pack two fp32 -> bf16x2 in one v_perm_b32: result = {hi16(ub),hi16(ua)}
__device__ __forceinline__ unsigned pack_bf16x2(float a, float b) {
  unsigned ua = __builtin_bit_cast(unsigned, a) + 0x8000u;
  unsigned ub = __builtin_bit_cast(unsigned, b) + 0x8000u;
  return __builtin_amdgcn_perm(ub, ua, 0x07060302u);
}

// ---------------- fused fp32 -> bf16 convert (x, w_qkv, w_proj) ----------------
__global__ void tobf16_all(const float* __restrict__ x, const float* __restrict__ wq,
                           const float* __restrict__ wp, bf16_t* __restrict__ xb,
                           bf16_t* __restrict__ wqb, bf16_t* __restrict__ wpb) {
  int bid = blockIdx.x;
  const float* in;
  bf16_t* out;
  int base;
  if (bid < 4096) { in = x; out = xb; base = bid; }
  else if (bid < 7168) { in = wq; out = wqb; base = bid - 4096; }
  else { in = wp; out = wpb; base = bid - 7168; }
  int i = base * 256 + threadIdx.x;  // all three sizes are exact multiples of 256 float4
  float4 v = ((const float4*)in)[i];
  uint2 o;
  o.x = pack_bf16x2(v.x, v.y);
  o.y = pack_bf16x2(v.z, v.w);
  ((uint2*)out)[i] = o;
}

// ---------------- GEMM: C[M,N] = A[M,K] @ B[N,K]^T + bias ----------------
// 128xBN tile, BK=32, 256 threads (4 waves 2x2), double-buffered, one barrier
// per k-iter (drains DMA issued a full iter earlier). 16B-unit XOR swizzle.
// EPI=0: QKV epilogue (scatter to q/k/vT bf16 layouts, q pre-scaled), BN=128
// EPI=1: proj epilogue (fp32 out), BN=64 for 2x grid
template <int EPI, int BN>
__global__ __launch_bounds__(256, 2) void gemm_bt(
    const bf16_t* __restrict__ A, const bf16_t* __restrict__ Bm,
    const float* __restrict__ bias,
    bf16_t* __restrict__ qb, bf16_t* __restrict__ kb, bf16_t* __restrict__ vtb,
    float* __restrict__ outf) {
  constexpr int NI = BN / 32;            // n-fragments per wave
  constexpr int BUF = 8192 + BN * 64;    // bytes per buffer: A 8 KB + B BN*64
  __shared__ __align__(16) char smem[2 * BUF];
  const int tid = threadIdx.x;
  const int w = tid >> 6, lane = tid & 63;
  const int wm = w >> 1, wn = w & 1;
  const int quad = lane >> 4, l15 = lane & 15;
  const int m0 = blockIdx.y * 128, n0 = blockIdx.x * BN;

  auto stage = [&](int kt, int bb) {
    char* bA = smem + bb * BUF;
    char* bB = bA + 8192;
#pragma unroll
    for (int i = 0; i < 2; i++) {  // A: 512 units
      int ub = w * 128 + i * 64;
      int u = ub + lane;
      int r = u >> 2, c = (u & 3) ^ ((r >> 1) & 3);
      load_lds16(A + (size_t)(m0 + r) * 1024 + kt + c * 8, bA + (size_t)ub * 16);
    }
#pragma unroll
    for (int i = 0; i < BN / 64; i++) {  // B: BN*4 units
      int ub = w * (BN / 64) * 64 + i * 64;
      int u = ub + lane;
      int r = u >> 2, c = (u & 3) ^ ((r >> 1) & 3);
      load_lds16(Bm + (size_t)(n0 + r) * 1024 + kt + c * 8, bB + (size_t)ub * 16);
    }
  };

  f32x4 acc[4][NI];
#pragma unroll
  for (int mi = 0; mi < 4; mi++)
#pragma unroll
    for (int ni = 0; ni < NI; ni++) acc[mi][ni] = (f32x4){0.f, 0.f, 0.f, 0.f};

  stage(0, 0);  // prologue

  for (int it = 0; it < 32; it++) {
    __syncthreads();  // drains buf-it DMA (issued a full iter ago) + reuse sync
    if (it < 31) stage((it + 1) * 32, (it + 1) & 1);
    const bf16_t* bA = (const bf16_t*)(smem + (it & 1) * BUF);
    const bf16_t* bB = (const bf16_t*)(smem + (it & 1) * BUF + 8192);

    bf16x8 af[4], bfr[NI];
#pragma unroll
    for (int mi = 0; mi < 4; mi++) {
      int r = wm * 64 + mi * 16 + l15;
      af[mi] = *(const bf16x8*)(bA + (r * 4 + (quad ^ ((r >> 1) & 3))) * 8);
    }
#pragma unroll
    for (int ni = 0; ni < NI; ni++) {
      int r = wn * (BN / 2) + ni * 16 + l15;
      bfr[ni] = *(const bf16x8*)(bB + (r * 4 + (quad ^ ((r >> 1) & 3))) * 8);
    }
#pragma unroll
    for (int mi = 0; mi < 4; mi++)
#pragma unroll
      for (int ni = 0; ni < NI; ni++)
        acc[mi][ni] = __builtin_amdgcn_mfma_f32_16x16x32_bf16(af[mi], bfr[ni], acc[mi][ni], 0, 0, 0);
  }

  // epilogue: C row = m0+wm*64+mi*16+quad*4+r, col = n0+wn*(BN/2)+ni*16+l15
#pragma unroll
  for (int mi = 0; mi < 4; mi++) {
#pragma unroll
    for (int ni = 0; ni < NI; ni++) {
      int n = n0 + wn * (BN / 2) + ni * 16 + l15;
      float bv = bias[n];
#pragma unroll
      for (int r = 0; r < 4; r++) {
        int m = m0 + wm * 64 + mi * 16 + quad * 4 + r;
        float v = acc[mi][ni][r] + bv;
        if (EPI == 0) {
          int t = n >> 10;           // 0=Q,1=K,2=V (uniform per block: 128 | 1024)
          int rr = n & 1023;
          int hh = rr >> 6, d = rr & 63;
          int bb = m >> 11, s = m & 2047;
          size_t bh = (size_t)(bb * H_ + hh);
          if (t == 0)
            qb[(bh * S_ + s) * HD_ + d] = fbf16(v * QSCALE);
          else if (t == 1)
            kb[(bh * S_ + s) * HD_ + d] = fbf16(v);
          else
            vtb[(bh * HD_ + d) * S_ + s] = fbf16(v);  // V transposed for PV B-operand
        } else {
          outf[(size_t)m * 1024 + n] = v;
        }
      }
    }
  }
}

// ---------------- flash attention (S^T form, kv-split, 2-stage pipelined) -------
// 1D grid of 1024; gid%8 = XCD: XCD g owns bh in [4g,4g+4) -> 2 MB K/V per XCD.
// block = (b,h, q-tile 64), 256 threads = 4 waves:
//   wave w: q-band (w&1)*32, kv-half (w>>1)*1024.  Each pair (waves 2p,2p+1)
//   runs its own dbuf pipeline over 32 kv-tiles of 32 (16 KB LDS per pair).
// S^T = K Q^T: A = K rows (m=kv 0..31, LDS), B = Q rows (n=q, regs).
// C/D 32x32: col=lane&31=q, row=kv=(reg&3)+8*(reg>>2)+4*h2  [m74/m101 layout].
// PIPELINE: iter j holds S_cur=S(j); av(j) read PRE-barrier (protects regs
// from stage(j+2) -> buf j&1), then barrier, stage(j+2), ak(j+1) reads +
// S(j+1) MFMAs | softmax(j) | PV(j). Single body, s_cur=s_next copy (~16
// v_mov, measured cheaper than every alternative tried -- see header).
// Max-free softmax => pair partials (O^T, l) combine by addition via LDS.
__global__ __launch_bounds__(256, 4) void attn(
    const bf16_t* __restrict__ qb, const bf16_t* __restrict__ kb,
    const bf16_t* __restrict__ vtb, bf16_t* __restrict__ ob) {
  __shared__ __align__(16) char smem[32768];
  const int tid = threadIdx.x, w = tid >> 6, lane = tid & 63;
  const int h2 = lane >> 5, l31 = lane & 31;
  const int qband = w & 1, pair = w >> 1;
  // XCD-aware decode: gid%8 = XCD; 4 bh x 32 q-tiles per XCD.
  const int gid = blockIdx.x;
  const int g = gid & 7, k_ = gid >> 3;
  const int bh = g * 4 + (k_ >> 5);
  const int qt = k_ & 31;
  const int b = bh >> 4, h = bh & 15;
  const size_t base = (size_t)bh * S_ * HD_;
  const size_t vbase = (size_t)bh * HD_ * S_;
  const int q0 = qt * 64;
  const int myq = q0 + qband * 32 + l31;  // this lane's q column
  const int kvbase = pair << 10;          // this wave's kv-half
  char* pbase = smem + pair * 16384;      // per-pair LDS: 2 bufs x (K 4K | V 4K)

  // Q B-frags (loop-invariant): B[n=q=l31][k=ks*16+h2*8+j]
  bf16x8 bq[4];
#pragma unroll
  for (int ks = 0; ks < 4; ks++)
    bq[ks] = *(const bf16x8*)(qb + base + (size_t)myq * 64 + ks * 16 + h2 * 8);

  // stage K[32 kv x 64 d] + V^T[64 d x 32 kv] into pair buffer bb.
  // K rows: 8 units/row, sigma(r)=r&7. V rows: 4 units/row, sigma(r)=(r>>1)&3.
  auto stage = [&](int kv0, int bb) {
    char* bK = pbase + bb * 8192;
    char* bV = bK + 4096;
#pragma unroll
    for (int i = 0; i < 2; i++) {
      int ub = qband * 64 + i * 128;
      int u = ub + lane;
      {
        int r = u >> 3, c = (u & 7) ^ (r & 7);
        load_lds16(kb + base + (size_t)(kv0 + r) * 64 + c * 8, bK + (size_t)ub * 16);
      }
      {
        int r = u >> 2, c = (u & 3) ^ ((r >> 1) & 3);
        load_lds16(vtb + vbase + (size_t)r * S_ + kv0 + c * 8, bV + (size_t)ub * 16);
      }
    }
  };

  f32x16 acc_o[2];
#pragma unroll
  for (int dt = 0; dt < 2; dt++)
#pragma unroll
    for (int i = 0; i < 16; i++) acc_o[dt][i] = 0.f;
  float l_acc = 0.f;  // per-lane: sum of p over this lane's kv rows, for q=myq

  // prologue: tile 0 staged+drained; tile 1 DMA in flight; s_cur = S(0)
  stage(kvbase, 0);
  __syncthreads();
  stage(kvbase + 32, 1);
  f32x16 s_cur;
  {
    const bf16_t* bK = (const bf16_t*)pbase;
#pragma unroll
    for (int i = 0; i < 16; i++) s_cur[i] = 0.f;
#pragma unroll
    for (int ks = 0; ks < 4; ks++) {
      int r = l31, c = ks * 2 + h2;
      bf16x8 ak = *(const bf16x8*)(bK + (r * 8 + (c ^ (r & 7))) * 8);
      s_cur = __builtin_amdgcn_mfma_f32_32x32x16_bf16(ak, bq[ks], s_cur, 0, 0, 0);
    }
  }

  for (int j = 0; j < 32; j++) {
    // V^T(j) A-frags PRE-barrier: tile j was drained at the previous barrier;
    // regs protect against stage(j+2) overwriting buf j&1 mid-iter.
    const bf16_t* bV = (const bf16_t*)(pbase + (j & 1) * 8192 + 4096);
    bf16x8 av[2][2];
#pragma unroll
    for (int ks = 0; ks < 2; ks++)
#pragma unroll
      for (int dt = 0; dt < 2; dt++) {
        int r = dt * 32 + l31, c = ks * 2 + h2;
        av[dt][ks] = *(const bf16x8*)(bV + (r * 4 + (c ^ ((r >> 1) & 3))) * 8);
      }

    __syncthreads();  // drains stage(j+1) DMA; all waves' av(j)/ak(j) reads done
    if (j < 30) stage(kvbase + (j + 2) * 32, j & 1);

    // S(j+1) = K(j+1) Q^T — independent of softmax(j) and PV(j)
    f32x16 s_next;
    if (j < 31) {
      const bf16_t* bK1 = (const bf16_t*)(pbase + ((j + 1) & 1) * 8192);
#pragma unroll
      for (int i = 0; i < 16; i++) s_next[i] = 0.f;
#pragma unroll
      for (int ks = 0; ks < 4; ks++) {
        int r = l31, c = ks * 2 + h2;
        bf16x8 ak = *(const bf16x8*)(bK1 + (r * 8 + (c ^ (r & 7))) * 8);
        s_next = __builtin_amdgcn_mfma_f32_32x32x16_bf16(ak, bq[ks], s_next, 0, 0, 0);
      }
    }

    // no-max softmax on s_cur (native exp2) + pack reg-pairs (adjacent kv)
    unsigned pk[8];
    float ls = 0.f;
#pragma unroll
    for (int i = 0; i < 8; i++) {
      float p0 = __builtin_amdgcn_exp2f(s_cur[2 * i]);
      float p1 = __builtin_amdgcn_exp2f(s_cur[2 * i + 1]);
      ls += p0 + p1;
      pk[i] = pack_bf16x2(p0, p1);
    }
    l_acc += ls;

    // build P^T B-frags: per 16-kv step, exchange packs across lane-halves.
    // permlane32_swap(a,b): dst0 = {a_lo | b_lo->hi}, dst1 = {a_hi->lo | b_hi}
    bf16x8 bp[2];
#pragma unroll
    for (int kk = 0; kk < 2; kk++) {
      unsigned a0 = pk[kk * 4 + 0], a1 = pk[kk * 4 + 1];
      unsigned a2 = pk[kk * 4 + 2], a3 = pk[kk * 4 + 3];
      u32x2 r02 = __builtin_amdgcn_permlane32_swap(a0, a2, false, false);
      u32x2 r13 = __builtin_amdgcn_permlane32_swap(a1, a3, false, false);
      union { unsigned u[4]; bf16x8 v; } bb;
      bb.u[0] = r02[0];
      bb.u[1] = r13[0];
      bb.u[2] = r02[1];
      bb.u[3] = r13[1];
      bp[kk] = bb.v;
    }

    // O^T += V^T(j) P^T(j)
#pragma unroll
    for (int ks = 0; ks < 2; ks++)
#pragma unroll
      for (int dt = 0; dt < 2; dt++)
        acc_o[dt] = __builtin_amdgcn_mfma_f32_32x32x16_bf16(av[dt][ks], bp[ks], acc_o[dt], 0, 0, 0);

    if (j < 31) s_cur = s_next;
  }

  // within-pair denominator: lane + h2-partner cover all kv rows of this half
  float l_pair = l_acc + (float)__shfl_xor(l_acc, 32);

  // cross-pair combine via LDS (K/V buffers dead after last in-loop barrier).
  // stride 33 floats -> conflict-free. Region: 2 qbands x 64 lanes x 33 f32.
  float* red = (float*)smem;
  const int rbase = qband * (64 * 33) + lane * 33;
  if (pair == 1) {
#pragma unroll
    for (int dt = 0; dt < 2; dt++)
#pragma unroll
      for (int i = 0; i < 16; i++) red[rbase + dt * 16 + i] = acc_o[dt][i];
    red[rbase + 32] = l_pair;
  }
  __syncthreads();
  if (pair == 0) {
#pragma unroll
    for (int dt = 0; dt < 2; dt++)
#pragma unroll
      for (int i = 0; i < 16; i++) acc_o[dt][i] += red[rbase + dt * 16 + i];
    float inv = 1.0f / (l_pair + red[rbase + 32]);

    // epilogue: O^T col q = myq (lane), rows d = dt*32 + 8*g4 + 4*h2 + (0..3)
#pragma unroll
    for (int dt = 0; dt < 2; dt++)
#pragma unroll
      for (int g4 = 0; g4 < 4; g4++) {
        uint2 o;
        o.x = pack_bf16x2(acc_o[dt][g4 * 4 + 0] * inv, acc_o[dt][g4 * 4 + 1] * inv);
        o.y = pack_bf16x2(acc_o[dt][g4 * 4 + 2] * inv, acc_o[dt][g4 * 4 + 3] * inv);
        int d = dt * 32 + g4 * 8 + h2 * 4;
        *(uint2*)(ob + ((size_t)b * S_ + myq) * D_ + h * HD_ + d) = o;
      }
  }
}

// ---------------- launcher ----------------
extern "C" void kernel_launch(void* const* d_in, const int* in_sizes, int n_in,
                              void* d_out, int out_size, void* d_ws, size_t ws_size,
                              hipStream_t stream) {
  const float* x = (const float*)d_in[0];        // [2,2048,1024]
  const float* w_qkv = (const float*)d_in[1];    // [3072,1024]
  const float* b_qkv = (const float*)d_in[2];    // [3072]
  const float* w_proj = (const float*)d_in[3];   // [1024,1024]
  const float* b_proj = (const float*)d_in[4];   // [1024]
  float* out = (float*)d_out;

  char* ws = (char*)d_ws;
  size_t off = 0;
  bf16_t* xb = (bf16_t*)(ws + off); off += (size_t)4096 * 1024 * 2;    // 8 MB
  bf16_t* wqkvb = (bf16_t*)(ws + off); off += (size_t)3072 * 1024 * 2; // 6 MB
  bf16_t* wpb = (bf16_t*)(ws + off); off += (size_t)1024 * 1024 * 2;   // 2 MB
  bf16_t* qb = (bf16_t*)(ws + off); off += (size_t)4096 * 1024 * 2;    // 8 MB [B,H,S,hd]
  bf16_t* kb = (bf16_t*)(ws + off); off += (size_t)4096 * 1024 * 2;    // 8 MB [B,H,S,hd]
  bf16_t* vtb = (bf16_t*)(ws + off); off += (size_t)4096 * 1024 * 2;   // 8 MB [B,H,hd,S]
  bf16_t* ob = xb;  // xb dead after QKV GEMM; reuse for attention output
  // total ws use: 41,943,040 B

  tobf16_all<<<8192, 256, 0, stream>>>(x, w_qkv, w_proj, xb, wqkvb, wpb);
  gemm_bt<0, 128><<<dim3(24, 32), 256, 0, stream>>>(xb, wqkvb, b_qkv, qb, kb, vtb, nullptr);
  attn<<<1024, 256, 0, stream>>>(qb, kb, vtb, ob);
  gemm_bt<1, 64><<<dim3(16, 32), 256, 0, stream>>>(ob, wpb, b_proj, nullptr, nullptr, nullptr, out);
}

// Round 8
// 185.303 us; speedup vs baseline: 1.5794x; 1.0227x over previous
//
#include <hip/hip_runtime.h>
#include <hip/hip_bf16.h>
#include <math.h>

// MultiHeadSelfAttention: B=2,S=2048,D=1024,H=16,hd=64, fp32 in/out.
// bf16 MFMA everywhere; flash attention (S^T form) with no-max softmax.
// R19 = R18 attn (parked at measured optimum) + GEMM-side changes:
//  a) gemm_bt launch_bounds (256,2) -> (256,4): 2 -> 4 blocks/CU. GEMM
//     blocks don't share barriers, so co-resident blocks hide each other's
//     barrier-drain (m97 implicit pipeline; same mechanism as R12's attn
//     occupancy win, +18%). LDS 32KB/block -> 4 fit in 160KB.
//     SPILL WATCH: if gemm enters top-5 with inflated WRITE_SIZE, the
//     128-reg cap spilled -> revert to (256,3).
//  b) V^T epilogue store vectorized: lane holds 4 consecutive s for fixed
//     d -> one 8B uint2 store instead of 4x 2B at 4KB stride (4x fewer
//     store instrs, ~4x less L2 partial-line write traffic).
// attn ledger (all measured): kv-split 2x occ WIN (63->51.7); ping-pong x2
// FAIL (scratch); setprio FAIL (58.9, barrier-locked waves). BANK_CONFLICT
// 4.19M = intrinsic b128 cost, not actionable.

typedef __bf16 bf16_t;
typedef __bf16 bf16x8 __attribute__((ext_vector_type(8)));
typedef float f32x4 __attribute__((ext_vector_type(4)));
typedef float f32x16 __attribute__((ext_vector_type(16)));
typedef unsigned u32x2 __attribute__((ext_vector_type(2)));

#define B_ 2
#define S_ 2048
#define D_ 1024
#define H_ 16
#define HD_ 64
// fold softmax scale (1/8) * log2(e) into Q so scores feed exp2 directly
#define QSCALE 0.18033688011112042f

__device__ __forceinline__ void load_lds16(const void* g, void* s) {
  // direct global->LDS DMA, 16B/lane; LDS dest is wave-uniform base + lane*16
  __builtin_amdgcn_global_load_lds((__attribute__((address_space(1))) unsigned int*)g,
                                   (__attribute__((address_space(3))) unsigned int*)s,
                                   16, 0, 0);
}

// fast fp32->bf16: round-to-nearest via +0x8000 (no NaN path; inputs finite).
__device__ __forceinline__ bf16_t fbf16(float x) {
  unsigned u = (__builtin_bit_cast(unsigned, x) + 0x8000u) >> 16;
  unsigned short s = (unsigned short)u;
  return __builtin_bit_cast(bf16_t, s);
}
// pack two fp32 -> bf16x2 in one v_perm_b32: result = {hi16(ub),hi16(ua)}
__device__ __forceinline__ unsigned pack_bf16x2(float a, float b) {
  unsigned ua = __builtin_bit_cast(unsigned, a) + 0x8000u;
  unsigned ub = __builtin_bit_cast(unsigned, b) + 0x8000u;
  return __builtin_amdgcn_perm(ub, ua, 0x07060302u);
}

// ---------------- fused fp32 -> bf16 convert (x, w_qkv, w_proj) ----------------
__global__ void tobf16_all(const float* __restrict__ x, const float* __restrict__ wq,
                           const float* __restrict__ wp, bf16_t* __restrict__ xb,
                           bf16_t* __restrict__ wqb, bf16_t* __restrict__ wpb) {
  int bid = blockIdx.x;
  const float* in;
  bf16_t* out;
  int base;
  if (bid < 4096) { in = x; out = xb; base = bid; }
  else if (bid < 7168) { in = wq; out = wqb; base = bid - 4096; }
  else { in = wp; out = wpb; base = bid - 7168; }
  int i = base * 256 + threadIdx.x;  // all three sizes are exact multiples of 256 float4
  float4 v = ((const float4*)in)[i];
  uint2 o;
  o.x = pack_bf16x2(v.x, v.y);
  o.y = pack_bf16x2(v.z, v.w);
  ((uint2*)out)[i] = o;
}

// ---------------- GEMM: C[M,N] = A[M,K] @ B[N,K]^T + bias ----------------
// 128xBN tile, BK=32, 256 threads (4 waves 2x2), double-buffered, one barrier
// per k-iter (drains DMA issued a full iter earlier). 16B-unit XOR swizzle.
// EPI=0: QKV epilogue (scatter to q/k/vT bf16 layouts, q pre-scaled), BN=128
// EPI=1: proj epilogue (fp32 out), BN=64 for 2x grid
// launch_bounds (256,4): 4 blocks/CU (LDS 32KB/block; reg cap 128 unified).
template <int EPI, int BN>
__global__ __launch_bounds__(256, 4) void gemm_bt(
    const bf16_t* __restrict__ A, const bf16_t* __restrict__ Bm,
    const float* __restrict__ bias,
    bf16_t* __restrict__ qb, bf16_t* __restrict__ kb, bf16_t* __restrict__ vtb,
    float* __restrict__ outf) {
  constexpr int NI = BN / 32;            // n-fragments per wave
  constexpr int BUF = 8192 + BN * 64;    // bytes per buffer: A 8 KB + B BN*64
  __shared__ __align__(16) char smem[2 * BUF];
  const int tid = threadIdx.x;
  const int w = tid >> 6, lane = tid & 63;
  const int wm = w >> 1, wn = w & 1;
  const int quad = lane >> 4, l15 = lane & 15;
  const int m0 = blockIdx.y * 128, n0 = blockIdx.x * BN;

  auto stage = [&](int kt, int bb) {
    char* bA = smem + bb * BUF;
    char* bB = bA + 8192;
#pragma unroll
    for (int i = 0; i < 2; i++) {  // A: 512 units
      int ub = w * 128 + i * 64;
      int u = ub + lane;
      int r = u >> 2, c = (u & 3) ^ ((r >> 1) & 3);
      load_lds16(A + (size_t)(m0 + r) * 1024 + kt + c * 8, bA + (size_t)ub * 16);
    }
#pragma unroll
    for (int i = 0; i < BN / 64; i++) {  // B: BN*4 units
      int ub = w * (BN / 64) * 64 + i * 64;
      int u = ub + lane;
      int r = u >> 2, c = (u & 3) ^ ((r >> 1) & 3);
      load_lds16(Bm + (size_t)(n0 + r) * 1024 + kt + c * 8, bB + (size_t)ub * 16);
    }
  };

  f32x4 acc[4][NI];
#pragma unroll
  for (int mi = 0; mi < 4; mi++)
#pragma unroll
    for (int ni = 0; ni < NI; ni++) acc[mi][ni] = (f32x4){0.f, 0.f, 0.f, 0.f};

  stage(0, 0);  // prologue

  for (int it = 0; it < 32; it++) {
    __syncthreads();  // drains buf-it DMA (issued a full iter ago) + reuse sync
    if (it < 31) stage((it + 1) * 32, (it + 1) & 1);
    const bf16_t* bA = (const bf16_t*)(smem + (it & 1) * BUF);
    const bf16_t* bB = (const bf16_t*)(smem + (it & 1) * BUF + 8192);

    bf16x8 af[4], bfr[NI];
#pragma unroll
    for (int mi = 0; mi < 4; mi++) {
      int r = wm * 64 + mi * 16 + l15;
      af[mi] = *(const bf16x8*)(bA + (r * 4 + (quad ^ ((r >> 1) & 3))) * 8);
    }
#pragma unroll
    for (int ni = 0; ni < NI; ni++) {
      int r = wn * (BN / 2) + ni * 16 + l15;
      bfr[ni] = *(const bf16x8*)(bB + (r * 4 + (quad ^ ((r >> 1) & 3))) * 8);
    }
#pragma unroll
    for (int mi = 0; mi < 4; mi++)
#pragma unroll
      for (int ni = 0; ni < NI; ni++)
        acc[mi][ni] = __builtin_amdgcn_mfma_f32_16x16x32_bf16(af[mi], bfr[ni], acc[mi][ni], 0, 0, 0);
  }

  // epilogue: C row = m0+wm*64+mi*16+quad*4+r, col = n0+wn*(BN/2)+ni*16+l15
#pragma unroll
  for (int mi = 0; mi < 4; mi++) {
#pragma unroll
    for (int ni = 0; ni < NI; ni++) {
      int n = n0 + wn * (BN / 2) + ni * 16 + l15;
      float bv = bias[n];
      int mrow = m0 + wm * 64 + mi * 16 + quad * 4;  // 4 consecutive m
      if (EPI == 0) {
        int t = n >> 10;           // 0=Q,1=K,2=V (uniform per block: 128 | 1024)
        int rr = n & 1023;
        int hh = rr >> 6, d = rr & 63;
        int bb = mrow >> 11, s = mrow & 2047;  // all 4 rows share bb (m0%128==0)
        size_t bh = (size_t)(bb * H_ + hh);
        if (t == 2) {
          // V^T: per lane, 4 consecutive s at fixed d -> one 8B store
          uint2 o;
          o.x = pack_bf16x2(acc[mi][ni][0] + bv, acc[mi][ni][1] + bv);
          o.y = pack_bf16x2(acc[mi][ni][2] + bv, acc[mi][ni][3] + bv);
          *(uint2*)(vtb + (bh * HD_ + d) * S_ + s) = o;
        } else if (t == 0) {
#pragma unroll
          for (int r = 0; r < 4; r++)
            qb[(bh * S_ + s + r) * HD_ + d] = fbf16((acc[mi][ni][r] + bv) * QSCALE);
        } else {
#pragma unroll
          for (int r = 0; r < 4; r++)
            kb[(bh * S_ + s + r) * HD_ + d] = fbf16(acc[mi][ni][r] + bv);
        }
      } else {
#pragma unroll
        for (int r = 0; r < 4; r++)
          outf[(size_t)(mrow + r) * 1024 + n] = acc[mi][ni][r] + bv;
      }
    }
  }
}

// ---------------- flash attention (S^T form, kv-split, 2-stage pipelined) -------
// 1D grid of 1024; gid%8 = XCD: XCD g owns bh in [4g,4g+4) -> 2 MB K/V per XCD.
// block = (b,h, q-tile 64), 256 threads = 4 waves:
//   wave w: q-band (w&1)*32, kv-half (w>>1)*1024.  Each pair (waves 2p,2p+1)
//   runs its own dbuf pipeline over 32 kv-tiles of 32 (16 KB LDS per pair).
// S^T = K Q^T: A = K rows (m=kv 0..31, LDS), B = Q rows (n=q, regs).
// C/D 32x32: col=lane&31=q, row=kv=(reg&3)+8*(reg>>2)+4*h2  [m74/m101 layout].
// PIPELINE: iter j holds S_cur=S(j); av(j) read PRE-barrier (protects regs
// from stage(j+2) -> buf j&1), then barrier, stage(j+2), ak(j+1) reads +
// S(j+1) MFMAs | softmax(j) | PV(j). Single body, s_cur=s_next copy (~16
// v_mov, measured cheaper than every alternative tried).
// Max-free softmax => pair partials (O^T, l) combine by addition via LDS.
__global__ __launch_bounds__(256, 4) void attn(
    const bf16_t* __restrict__ qb, const bf16_t* __restrict__ kb,
    const bf16_t* __restrict__ vtb, bf16_t* __restrict__ ob) {
  __shared__ __align__(16) char smem[32768];
  const int tid = threadIdx.x, w = tid >> 6, lane = tid & 63;
  const int h2 = lane >> 5, l31 = lane & 31;
  const int qband = w & 1, pair = w >> 1;
  // XCD-aware decode: gid%8 = XCD; 4 bh x 32 q-tiles per XCD.
  const int gid = blockIdx.x;
  const int g = gid & 7, k_ = gid >> 3;
  const int bh = g * 4 + (k_ >> 5);
  const int qt = k_ & 31;
  const int b = bh >> 4, h = bh & 15;
  const size_t base = (size_t)bh * S_ * HD_;
  const size_t vbase = (size_t)bh * HD_ * S_;
  const int q0 = qt * 64;
  const int myq = q0 + qband * 32 + l31;  // this lane's q column
  const int kvbase = pair << 10;          // this wave's kv-half
  char* pbase = smem + pair * 16384;      // per-pair LDS: 2 bufs x (K 4K | V 4K)

  // Q B-frags (loop-invariant): B[n=q=l31][k=ks*16+h2*8+j]
  bf16x8 bq[4];
#pragma unroll
  for (int ks = 0; ks < 4; ks++)
    bq[ks] = *(const bf16x8*)(qb + base + (size_t)myq * 64 + ks * 16 + h2 * 8);

  // stage K[32 kv x 64 d] + V^T[64 d x 32 kv] into pair buffer bb.
  // K rows: 8 units/row, sigma(r)=r&7. V rows: 4 units/row, sigma(r)=(r>>1)&3.
  auto stage = [&](int kv0, int bb) {
    char* bK = pbase + bb * 8192;
    char* bV = bK + 4096;
#pragma unroll
    for (int i = 0; i < 2; i++) {
      int ub = qband * 64 + i * 128;
      int u = ub + lane;
      {
        int r = u >> 3, c = (u & 7) ^ (r & 7);
        load_lds16(kb + base + (size_t)(kv0 + r) * 64 + c * 8, bK + (size_t)ub * 16);
      }
      {
        int r = u >> 2, c = (u & 3) ^ ((r >> 1) & 3);
        load_lds16(vtb + vbase + (size_t)r * S_ + kv0 + c * 8, bV + (size_t)ub * 16);
      }
    }
  };

  f32x16 acc_o[2];
#pragma unroll
  for (int dt = 0; dt < 2; dt++)
#pragma unroll
    for (int i = 0; i < 16; i++) acc_o[dt][i] = 0.f;
  float l_acc = 0.f;  // per-lane: sum of p over this lane's kv rows, for q=myq

  // prologue: tile 0 staged+drained; tile 1 DMA in flight; s_cur = S(0)
  stage(kvbase, 0);
  __syncthreads();
  stage(kvbase + 32, 1);
  f32x16 s_cur;
  {
    const bf16_t* bK = (const bf16_t*)pbase;
#pragma unroll
    for (int i = 0; i < 16; i++) s_cur[i] = 0.f;
#pragma unroll
    for (int ks = 0; ks < 4; ks++) {
      int r = l31, c = ks * 2 + h2;
      bf16x8 ak = *(const bf16x8*)(bK + (r * 8 + (c ^ (r & 7))) * 8);
      s_cur = __builtin_amdgcn_mfma_f32_32x32x16_bf16(ak, bq[ks], s_cur, 0, 0, 0);
    }
  }

  for (int j = 0; j < 32; j++) {
    // V^T(j) A-frags PRE-barrier: tile j was drained at the previous barrier;
    // regs protect against stage(j+2) overwriting buf j&1 mid-iter.
    const bf16_t* bV = (const bf16_t*)(pbase + (j & 1) * 8192 + 4096);
    bf16x8 av[2][2];
#pragma unroll
    for (int ks = 0; ks < 2; ks++)
#pragma unroll
      for (int dt = 0; dt < 2; dt++) {
        int r = dt * 32 + l31, c = ks * 2 + h2;
        av[dt][ks] = *(const bf16x8*)(bV + (r * 4 + (c ^ ((r >> 1) & 3))) * 8);
      }

    __syncthreads();  // drains stage(j+1) DMA; all waves' av(j)/ak(j) reads done
    if (j < 30) stage(kvbase + (j + 2) * 32, j & 1);

    // S(j+1) = K(j+1) Q^T — independent of softmax(j) and PV(j)
    f32x16 s_next;
    if (j < 31) {
      const bf16_t* bK1 = (const bf16_t*)(pbase + ((j + 1) & 1) * 8192);
#pragma unroll
      for (int i = 0; i < 16; i++) s_next[i] = 0.f;
#pragma unroll
      for (int ks = 0; ks < 4; ks++) {
        int r = l31, c = ks * 2 + h2;
        bf16x8 ak = *(const bf16x8*)(bK1 + (r * 8 + (c ^ (r & 7))) * 8);
        s_next = __builtin_amdgcn_mfma_f32_32x32x16_bf16(ak, bq[ks], s_next, 0, 0, 0);
      }
    }

    // no-max softmax on s_cur (native exp2) + pack reg-pairs (adjacent kv)
    unsigned pk[8];
    float ls = 0.f;
#pragma unroll
    for (int i = 0; i < 8; i++) {
      float p0 = __builtin_amdgcn_exp2f(s_cur[2 * i]);
      float p1 = __builtin_amdgcn_exp2f(s_cur[2 * i + 1]);
      ls += p0 + p1;
      pk[i] = pack_bf16x2(p0, p1);
    }
    l_acc += ls;

    // build P^T B-frags: per 16-kv step, exchange packs across lane-halves.
    // permlane32_swap(a,b): dst0 = {a_lo | b_lo->hi}, dst1 = {a_hi->lo | b_hi}
    bf16x8 bp[2];
#pragma unroll
    for (int kk = 0; kk < 2; kk++) {
      unsigned a0 = pk[kk * 4 + 0], a1 = pk[kk * 4 + 1];
      unsigned a2 = pk[kk * 4 + 2], a3 = pk[kk * 4 + 3];
      u32x2 r02 = __builtin_amdgcn_permlane32_swap(a0, a2, false, false);
      u32x2 r13 = __builtin_amdgcn_permlane32_swap(a1, a3, false, false);
      union { unsigned u[4]; bf16x8 v; } bb;
      bb.u[0] = r02[0];
      bb.u[1] = r13[0];
      bb.u[2] = r02[1];
      bb.u[3] = r13[1];
      bp[kk] = bb.v;
    }

    // O^T += V^T(j) P^T(j)
#pragma unroll
    for (int ks = 0; ks < 2; ks++)
#pragma unroll
      for (int dt = 0; dt < 2; dt++)
        acc_o[dt] = __builtin_amdgcn_mfma_f32_32x32x16_bf16(av[dt][ks], bp[ks], acc_o[dt], 0, 0, 0);

    if (j < 31) s_cur = s_next;
  }

  // within-pair denominator: lane + h2-partner cover all kv rows of this half
  float l_pair = l_acc + (float)__shfl_xor(l_acc, 32);

  // cross-pair combine via LDS (K/V buffers dead after last in-loop barrier).
  // stride 33 floats -> conflict-free. Region: 2 qbands x 64 lanes x 33 f32.
  float* red = (float*)smem;
  const int rbase = qband * (64 * 33) + lane * 33;
  if (pair == 1) {
#pragma unroll
    for (int dt = 0; dt < 2; dt++)
#pragma unroll
      for (int i = 0; i < 16; i++) red[rbase + dt * 16 + i] = acc_o[dt][i];
    red[rbase + 32] = l_pair;
  }
  __syncthreads();
  if (pair == 0) {
#pragma unroll
    for (int dt = 0; dt < 2; dt++)
#pragma unroll
      for (int i = 0; i < 16; i++) acc_o[dt][i] += red[rbase + dt * 16 + i];
    float inv = 1.0f / (l_pair + red[rbase + 32]);

    // epilogue: O^T col q = myq (lane), rows d = dt*32 + 8*g4 + 4*h2 + (0..3)
#pragma unroll
    for (int dt = 0; dt < 2; dt++)
#pragma unroll
      for (int g4 = 0; g4 < 4; g4++) {
        uint2 o;
        o.x = pack_bf16x2(acc_o[dt][g4 * 4 + 0] * inv, acc_o[dt][g4 * 4 + 1] * inv);
        o.y = pack_bf16x2(acc_o[dt][g4 * 4 + 2] * inv, acc_o[dt][g4 * 4 + 3] * inv);
        int d = dt * 32 + g4 * 8 + h2 * 4;
        *(uint2*)(ob + ((size_t)b * S_ + myq) * D_ + h * HD_ + d) = o;
      }
  }
}

// ---------------- launcher ----------------
extern "C" void kernel_launch(void* const* d_in, const int* in_sizes, int n_in,
                              void* d_out, int out_size, void* d_ws, size_t ws_size,
                              hipStream_t stream) {
  const float* x = (const float*)d_in[0];        // [2,2048,1024]
  const float* w_qkv = (const float*)d_in[1];    // [3072,1024]
  const float* b_qkv = (const float*)d_in[2];    // [3072]
  const float* w_proj = (const float*)d_in[3];   // [1024,1024]
  const float* b_proj = (const float*)d_in[4];   // [1024]
  float* out = (float*)d_out;

  char* ws = (char*)d_ws;
  size_t off = 0;
  bf16_t* xb = (bf16_t*)(ws + off); off += (size_t)4096 * 1024 * 2;    // 8 MB
  bf16_t* wqkvb = (bf16_t*)(ws + off); off += (size_t)3072 * 1024 * 2; // 6 MB
  bf16_t* wpb = (bf16_t*)(ws + off); off += (size_t)1024 * 1024 * 2;   // 2 MB
  bf16_t* qb = (bf16_t*)(ws + off); off += (size_t)4096 * 1024 * 2;    // 8 MB [B,H,S,hd]
  bf16_t* kb = (bf16_t*)(ws + off); off += (size_t)4096 * 1024 * 2;    // 8 MB [B,H,S,hd]
  bf16_t* vtb = (bf16_t*)(ws + off); off += (size_t)4096 * 1024 * 2;   // 8 MB [B,H,hd,S]
  bf16_t* ob = xb;  // xb dead after QKV GEMM; reuse for attention output
  // total ws use: 41,943,040 B

  tobf16_all<<<8192, 256, 0, stream>>>(x, w_qkv, w_proj, xb, wqkvb, wpb);
  gemm_bt<0, 128><<<dim3(24, 32), 256, 0, stream>>>(xb, wqkvb, b_qkv, qb, kb, vtb, nullptr);
  attn<<<1024, 256, 0, stream>>>(qb, kb, vtb, ob);
  gemm_bt<1, 64><<<dim3(16, 32), 256, 0, stream>>>(ob, wpb, b_proj, nullptr, nullptr, nullptr, out);
}